// Round 1
// baseline (587.134 us; speedup 1.0000x reference)
//
#include <hip/hip_runtime.h>
#include <hip/hip_bf16.h>

#define NN 50000
#define EE 400000

// ---------------- small prep: fold a-vectors through W ----------------
__global__ void prep_vectors(const float* __restrict__ W_node, const float* __restrict__ W_edge,
                             const float* __restrict__ a_node, const float* __restrict__ a_edge,
                             float* wn_a1, float* wn_a2, float* wn_e1, float* we_a2) {
    int t = threadIdx.x;
    if (t < 256) {
        float x1 = 0.f, x2 = 0.f, x3 = 0.f;
        for (int j = 0; j < 128; ++j) {
            float w = W_node[t * 128 + j];
            x1 += w * a_node[j];
            x2 += w * a_node[128 + j];
            x3 += w * a_edge[j];
        }
        wn_a1[t] = x1; wn_a2[t] = x2; wn_e1[t] = x3;
    }
    if (t < 128) {
        float x = 0.f;
        for (int j = 0; j < 128; ++j) x += W_edge[t * 128 + j] * a_edge[128 + j];
        we_a2[t] = x;
    }
}

// ---------------- tiled f32 GEMM: C[M][128] = A[M][K] @ B[K][128] ----------------
template <int K>
__global__ __launch_bounds__(256) void gemm_f32(const float* __restrict__ A, const float* __restrict__ B,
                                                float* __restrict__ C, int M) {
    constexpr int BM = 64, BN = 128, BK = 32;
    __shared__ float As[BM][BK];
    __shared__ float Bs[BK][BN];
    int t = threadIdx.x;
    int bm = blockIdx.x * BM;
    int tx = t & 31, ty = t >> 5;  // tx: col-chunk 0..31 (4 cols each), ty: row group 0..7 (8 rows)
    float acc[8][4] = {};
    for (int k0 = 0; k0 < K; k0 += BK) {
        for (int c = t; c < BM * BK / 4; c += 256) {
            int row = c >> 3, pos = (c & 7) << 2;
            float4 v = make_float4(0.f, 0.f, 0.f, 0.f);
            int gr = bm + row;
            if (gr < M) v = *reinterpret_cast<const float4*>(A + (size_t)gr * K + k0 + pos);
            *reinterpret_cast<float4*>(&As[row][pos]) = v;
        }
        for (int c = t; c < BK * BN / 4; c += 256) {
            int row = c >> 5, pos = (c & 31) << 2;
            *reinterpret_cast<float4*>(&Bs[row][pos]) =
                *reinterpret_cast<const float4*>(B + (size_t)(k0 + row) * BN + pos);
        }
        __syncthreads();
#pragma unroll
        for (int kk = 0; kk < BK; ++kk) {
            float b0 = Bs[kk][tx * 4 + 0], b1 = Bs[kk][tx * 4 + 1];
            float b2 = Bs[kk][tx * 4 + 2], b3 = Bs[kk][tx * 4 + 3];
#pragma unroll
            for (int r = 0; r < 8; ++r) {
                float a = As[ty * 8 + r][kk];
                acc[r][0] += a * b0; acc[r][1] += a * b1;
                acc[r][2] += a * b2; acc[r][3] += a * b3;
            }
        }
        __syncthreads();
    }
#pragma unroll
    for (int r = 0; r < 8; ++r) {
        int gr = bm + ty * 8 + r;
        if (gr < M) *reinterpret_cast<float4*>(C + (size_t)gr * 128 + tx * 4) =
            *reinterpret_cast<const float4*>(acc[r]);
    }
}

// ---------------- per-node scalars s1,s2,t1 (wave per row, K=256) ----------------
__global__ void node_scalars(const float* __restrict__ NF, const float* __restrict__ w1,
                             const float* __restrict__ w2, const float* __restrict__ w3,
                             float* __restrict__ s1, float* __restrict__ s2, float* __restrict__ t1) {
    int wave = (int)((blockIdx.x * (size_t)blockDim.x + threadIdx.x) >> 6);
    int lane = threadIdx.x & 63;
    if (wave >= NN) return;
    const float* row = NF + (size_t)wave * 256;
    float4 v = *reinterpret_cast<const float4*>(row + lane * 4);
    float a = 0.f, b = 0.f, c = 0.f;
    const float* x = reinterpret_cast<const float*>(&v);
#pragma unroll
    for (int j = 0; j < 4; ++j) {
        a += x[j] * w1[lane * 4 + j];
        b += x[j] * w2[lane * 4 + j];
        c += x[j] * w3[lane * 4 + j];
    }
    for (int off = 32; off; off >>= 1) {
        a += __shfl_down(a, off);
        b += __shfl_down(b, off);
        c += __shfl_down(c, off);
    }
    if (lane == 0) { s1[wave] = a; s2[wave] = b; t1[wave] = c; }
}

// ---------------- per-edge scalar t2e (wave per row, K=128) ----------------
__global__ void edge_scalar(const float* __restrict__ EF, const float* __restrict__ w,
                            float* __restrict__ t2e) {
    int wave = (int)((blockIdx.x * (size_t)blockDim.x + threadIdx.x) >> 6);
    int lane = threadIdx.x & 63;
    if (wave >= EE) return;
    float2 v = *reinterpret_cast<const float2*>(EF + (size_t)wave * 128 + lane * 2);
    float a = v.x * w[lane * 2] + v.y * w[lane * 2 + 1];
    for (int off = 32; off; off >>= 1) a += __shfl_down(a, off);
    if (lane == 0) t2e[wave] = a;
}

// ---------------- per-edge attention + segment sums + counts ----------------
__global__ void attention(const int* __restrict__ edges, const float* __restrict__ s1,
                          const float* __restrict__ s2, const float* __restrict__ t1,
                          const float* __restrict__ t2e, float* __restrict__ natt,
                          float* __restrict__ eatt, float* __restrict__ nsum,
                          float* __restrict__ esum, int* __restrict__ counts) {
    int i = blockIdx.x * blockDim.x + threadIdx.x;
    if (i >= 2 * EE) return;
    int s, d, j;
    if (i < EE) { j = i; s = edges[2 * j]; d = edges[2 * j + 1]; }
    else        { j = i - EE; s = edges[2 * j + 1]; d = edges[2 * j]; }
    float xn = s1[s] + s2[d];
    xn = xn >= 0.f ? xn : 0.2f * xn;
    xn = fminf(fmaxf(xn, -2.f), 2.f);
    float na = expf(xn);
    float xe = t1[s] + t2e[j];
    xe = xe >= 0.f ? xe : 0.2f * xe;
    xe = fminf(fmaxf(xe, -2.f), 2.f);
    float ea = expf(xe);
    natt[i] = na; eatt[i] = ea;
    atomicAdd(&nsum[s], na);
    atomicAdd(&esum[s], ea);
    atomicAdd(&counts[s], 1);
}

// ---------------- scan: counts -> offsets (exclusive), cursor copy ----------------
#define SCAN_CHUNK 2048
__global__ void scan_block_sums(const int* __restrict__ counts, int* __restrict__ bsums) {
    __shared__ int sdata[256];
    int b = blockIdx.x, t = threadIdx.x;
    int base = b * SCAN_CHUNK + t * 8;
    int s = 0;
    for (int j = 0; j < 8; ++j) { int idx = base + j; if (idx < NN) s += counts[idx]; }
    sdata[t] = s; __syncthreads();
    for (int off = 128; off; off >>= 1) { if (t < off) sdata[t] += sdata[t + off]; __syncthreads(); }
    if (t == 0) bsums[b] = sdata[0];
}
__global__ void scan_bsums(int* __restrict__ bsums, int nb) {
    if (threadIdx.x == 0 && blockIdx.x == 0) {
        int run = 0;
        for (int i = 0; i < nb; ++i) { int v = bsums[i]; bsums[i] = run; run += v; }
    }
}
__global__ void scan_final(const int* __restrict__ counts, const int* __restrict__ bsums,
                           int* __restrict__ offsets, int* __restrict__ cursor) {
    __shared__ int sdata[256];
    int b = blockIdx.x, t = threadIdx.x;
    int base = b * SCAN_CHUNK + t * 8;
    int loc[8]; int s = 0;
    for (int j = 0; j < 8; ++j) { int idx = base + j; int v = (idx < NN) ? counts[idx] : 0; loc[j] = v; s += v; }
    sdata[t] = s; __syncthreads();
    for (int off = 1; off < 256; off <<= 1) {
        int v = (t >= off) ? sdata[t - off] : 0;
        __syncthreads();
        sdata[t] += v;
        __syncthreads();
    }
    int run = sdata[t] - s + bsums[b];
    for (int j = 0; j < 8; ++j) {
        int idx = base + j;
        if (idx < NN) { offsets[idx] = run; cursor[idx] = run; run += loc[j]; }
    }
}

// ---------------- fill position->node map g ----------------
__global__ void fill_g(const int* __restrict__ offsets, const int* __restrict__ counts,
                       int* __restrict__ g) {
    int n = blockIdx.x * blockDim.x + threadIdx.x;
    if (n >= NN) return;
    int o = offsets[n], c = counts[n];
    for (int k = 0; k < c; ++k) g[o + k] = n;
}

// ---------------- CSR scatter (edge ids grouped by src) ----------------
__global__ void csr_scatter(const int* __restrict__ edges, int* __restrict__ cursor,
                            int* __restrict__ csr) {
    int i = blockIdx.x * blockDim.x + threadIdx.x;
    if (i >= 2 * EE) return;
    int s = (i < EE) ? edges[2 * i] : edges[2 * (i - EE) + 1];
    int p = atomicAdd(&cursor[s], 1);
    csr[p] = i;
}

// ---------------- normalize + variance partials ----------------
__global__ void normalize_var(const float* __restrict__ natt, const float* __restrict__ eatt,
                              const float* __restrict__ nsum, const float* __restrict__ esum,
                              const int* __restrict__ g, float* __restrict__ nnorm,
                              float* __restrict__ enorm, double* __restrict__ acc) {
    int i = blockIdx.x * blockDim.x + threadIdx.x;
    float nn = 0.f, en = 0.f;
    if (i < 2 * EE) {
        int gi = g[i];
        nn = natt[i] / nsum[gi];
        en = eatt[i] / esum[gi];
        nnorm[i] = nn; enorm[i] = en;
    }
    double v[4] = { (double)nn, (double)nn * nn, (double)en, (double)en * en };
    __shared__ double sd[4][4];
    int lane = threadIdx.x & 63, wv = threadIdx.x >> 6;
#pragma unroll
    for (int q = 0; q < 4; ++q) {
        double x = v[q];
        for (int off = 32; off; off >>= 1) x += __shfl_down(x, off);
        if (lane == 0) sd[q][wv] = x;
    }
    __syncthreads();
    if (threadIdx.x < 4) {
        double x = sd[threadIdx.x][0] + sd[threadIdx.x][1] + sd[threadIdx.x][2] + sd[threadIdx.x][3];
        atomicAdd(&acc[threadIdx.x], x);
    }
}

// ---------------- CSR accumulate: wave per node ----------------
__global__ void accumulate(const int* __restrict__ csr, const int* __restrict__ offsets,
                           const int* __restrict__ counts, const int* __restrict__ edges,
                           const float* __restrict__ nnorm, const float* __restrict__ enorm,
                           const float* __restrict__ h_v, const float* __restrict__ e_v,
                           float* __restrict__ node_out, float* __restrict__ edge_out) {
    int wave = (int)((blockIdx.x * (size_t)blockDim.x + threadIdx.x) >> 6);
    int lane = threadIdx.x & 63;
    if (wave >= NN) return;
    int o = offsets[wave], c = counts[wave];
    float aNx = 0.f, aNy = 0.f, aEx = 0.f, aEy = 0.f;
    for (int k = 0; k < c; ++k) {
        int i = csr[o + k];
        int d = (i < EE) ? edges[2 * i + 1] : edges[2 * (i - EE)];
        float nn = nnorm[i], en = enorm[i];
        float2 hv = *reinterpret_cast<const float2*>(h_v + (size_t)d * 128 + lane * 2);
        float2 ev = *reinterpret_cast<const float2*>(e_v + (size_t)d * 128 + lane * 2);
        aNx += hv.x * nn; aNy += hv.y * nn;
        aEx += ev.x * en; aEy += ev.y * en;
    }
    float2 rn = { aNx, aNy }, re = { aEx, aEy };
    *reinterpret_cast<float2*>(node_out + (size_t)wave * 128 + lane * 2) = rn;
    *reinterpret_cast<float2*>(edge_out + (size_t)wave * 128 + lane * 2) = re;
}

// ---------------- finalize variance ----------------
__global__ void finalize_var(const double* __restrict__ acc, float* __restrict__ out_var) {
    if (threadIdx.x == 0 && blockIdx.x == 0) {
        double M = 2.0 * EE;
        double nv = (acc[1] - acc[0] * acc[0] / M) / (M - 1.0);
        double ev = (acc[3] - acc[2] * acc[2] / M) / (M - 1.0);
        out_var[0] = (float)nv;
        out_var[1] = (float)ev;
    }
}

extern "C" void kernel_launch(void* const* d_in, const int* in_sizes, int n_in,
                              void* d_out, int out_size, void* d_ws, size_t ws_size,
                              hipStream_t stream) {
    const float* node_fts = (const float*)d_in[0];
    const float* edge_fts = (const float*)d_in[1];
    const int*   edges    = (const int*)d_in[2];
    const float* W_node   = (const float*)d_in[3];
    const float* W_edge   = (const float*)d_in[4];
    const float* a_node   = (const float*)d_in[5];
    const float* a_edge   = (const float*)d_in[6];
    float* out = (float*)d_out;

    char* w = (char*)d_ws;
    auto alloc = [&](size_t bytes) -> void* {
        void* p = (void*)w;
        w += (bytes + 255) & ~(size_t)255;
        return p;
    };
    float* h_v   = (float*)alloc((size_t)NN * 128 * 4);
    float* e_v   = (float*)alloc((size_t)NN * 128 * 4);
    float* s1    = (float*)alloc(NN * 4);
    float* s2    = (float*)alloc(NN * 4);
    float* t1    = (float*)alloc(NN * 4);
    float* t2e   = (float*)alloc(EE * 4);
    float* natt  = (float*)alloc(2 * EE * 4);
    float* eatt  = (float*)alloc(2 * EE * 4);
    float* nnorm = (float*)alloc(2 * EE * 4);
    float* enorm = (float*)alloc(2 * EE * 4);
    int*   offsets = (int*)alloc((NN + 1) * 4);
    int*   cursor  = (int*)alloc(NN * 4);
    int*   g       = (int*)alloc(2 * EE * 4);
    int*   csr     = (int*)alloc(2 * EE * 4);
    int*   bsums   = (int*)alloc(64 * 4);
    float* wn_a1 = (float*)alloc(256 * 4);
    float* wn_a2 = (float*)alloc(256 * 4);
    float* wn_e1 = (float*)alloc(256 * 4);
    float* we_a2 = (float*)alloc(128 * 4);
    // contiguous zero block: nsum, esum (floats), counts (ints), acc (4 doubles)
    char* zb = (char*)alloc(NN * 4 * 3 + 64);
    float* nsum = (float*)zb;
    float* esum = (float*)(zb + (size_t)NN * 4);
    int*   counts = (int*)(zb + (size_t)NN * 8);
    double* acc = (double*)(zb + (size_t)NN * 12);

    hipMemsetAsync(zb, 0, (size_t)NN * 12 + 64, stream);

    prep_vectors<<<1, 256, 0, stream>>>(W_node, W_edge, a_node, a_edge, wn_a1, wn_a2, wn_e1, we_a2);

    const int gemm_grid = (NN + 63) / 64;  // 782
    gemm_f32<256><<<gemm_grid, 256, 0, stream>>>(node_fts, W_node, h_v, NN);
    gemm_f32<128><<<gemm_grid, 256, 0, stream>>>(edge_fts, W_edge, e_v, NN);

    node_scalars<<<(NN + 3) / 4, 256, 0, stream>>>(node_fts, wn_a1, wn_a2, wn_e1, s1, s2, t1);
    edge_scalar<<<(EE + 3) / 4, 256, 0, stream>>>(edge_fts, we_a2, t2e);

    attention<<<(2 * EE + 255) / 256, 256, 0, stream>>>(edges, s1, s2, t1, t2e, natt, eatt, nsum, esum, counts);

    const int nscan = (NN + SCAN_CHUNK - 1) / SCAN_CHUNK;  // 25
    scan_block_sums<<<nscan, 256, 0, stream>>>(counts, bsums);
    scan_bsums<<<1, 64, 0, stream>>>(bsums, nscan);
    scan_final<<<nscan, 256, 0, stream>>>(counts, bsums, offsets, cursor);

    fill_g<<<(NN + 255) / 256, 256, 0, stream>>>(offsets, counts, g);
    csr_scatter<<<(2 * EE + 255) / 256, 256, 0, stream>>>(edges, cursor, csr);

    normalize_var<<<(2 * EE + 255) / 256, 256, 0, stream>>>(natt, eatt, nsum, esum, g, nnorm, enorm, acc);

    accumulate<<<(NN + 3) / 4, 256, 0, stream>>>(csr, offsets, counts, edges, nnorm, enorm,
                                                 h_v, e_v, out, out + (size_t)NN * 128);

    finalize_var<<<1, 64, 0, stream>>>(acc, out + (size_t)2 * NN * 128);
}

// Round 2
// 468.867 us; speedup vs baseline: 1.2522x; 1.2522x over previous
//
#include <hip/hip_runtime.h>
#include <hip/hip_bf16.h>

#define NN 50000
#define EE 400000

__device__ inline unsigned bf16pair(float a, float b) {
    unsigned ua = __float_as_uint(a), ub = __float_as_uint(b);
    ua = (ua + 0x7FFFu + ((ua >> 16) & 1u)) >> 16;
    ub = (ub + 0x7FFFu + ((ub >> 16) & 1u)) >> 16;
    return ua | (ub << 16);
}

// ---------------- small prep: fold a-vectors through W ----------------
__global__ void prep_vectors(const float* __restrict__ W_node, const float* __restrict__ W_edge,
                             const float* __restrict__ a_node, const float* __restrict__ a_edge,
                             float* wn_a1, float* wn_a2, float* wn_e1, float* we_a2) {
    int t = threadIdx.x;
    if (t < 256) {
        float x1 = 0.f, x2 = 0.f, x3 = 0.f;
        for (int j = 0; j < 128; ++j) {
            float w = W_node[t * 128 + j];
            x1 += w * a_node[j];
            x2 += w * a_node[128 + j];
            x3 += w * a_edge[j];
        }
        wn_a1[t] = x1; wn_a2[t] = x2; wn_e1[t] = x3;
    }
    if (t < 128) {
        float x = 0.f;
        for (int j = 0; j < 128; ++j) x += W_edge[t * 128 + j] * a_edge[128 + j];
        we_a2[t] = x;
    }
}

// ---------------- tiled f32 GEMM -> bf16 interleaved hev ----------------
// C[M][128] = A[M][K] @ B[K][128]; output written as bf16 pairs into hev:
// uint index within row = 2*(col/2) + OFFH   (OFFH=0: h half, OFFH=1: e half)
template <int K, int OFFH>
__global__ __launch_bounds__(256) void gemm_f32(const float* __restrict__ A, const float* __restrict__ B,
                                                unsigned* __restrict__ hevu, int M) {
    constexpr int BM = 64, BK = 32;
    __shared__ float Ast[BK][BM];     // transposed A tile
    __shared__ float Bs[BK][128];
    int t = threadIdx.x;
    int bm = blockIdx.x * BM;
    int tx = t & 15, ty = t >> 4;     // tx: 8-col group, ty: 4-row group
    float acc[4][8] = {};
    for (int k0 = 0; k0 < K; k0 += BK) {
        // stage A (transposed)
        for (int c = t; c < BM * BK / 4; c += 256) {
            int row = c >> 3, pos = (c & 7) << 2;
            float4 v = make_float4(0.f, 0.f, 0.f, 0.f);
            int gr = bm + row;
            if (gr < M) v = *reinterpret_cast<const float4*>(A + (size_t)gr * K + k0 + pos);
            Ast[pos + 0][row] = v.x; Ast[pos + 1][row] = v.y;
            Ast[pos + 2][row] = v.z; Ast[pos + 3][row] = v.w;
        }
        // stage B
        for (int c = t; c < BK * 128 / 4; c += 256) {
            int row = c >> 5, pos = (c & 31) << 2;
            *reinterpret_cast<float4*>(&Bs[row][pos]) =
                *reinterpret_cast<const float4*>(B + (size_t)(k0 + row) * 128 + pos);
        }
        __syncthreads();
#pragma unroll
        for (int kk = 0; kk < BK; ++kk) {
            float4 a = *reinterpret_cast<const float4*>(&Ast[kk][ty * 4]);
            float4 b0 = *reinterpret_cast<const float4*>(&Bs[kk][tx * 8]);
            float4 b1 = *reinterpret_cast<const float4*>(&Bs[kk][tx * 8 + 4]);
            const float* av = reinterpret_cast<const float*>(&a);
            const float* bv0 = reinterpret_cast<const float*>(&b0);
            const float* bv1 = reinterpret_cast<const float*>(&b1);
#pragma unroll
            for (int r = 0; r < 4; ++r) {
#pragma unroll
                for (int c = 0; c < 4; ++c) {
                    acc[r][c] += av[r] * bv0[c];
                    acc[r][c + 4] += av[r] * bv1[c];
                }
            }
        }
        __syncthreads();
    }
#pragma unroll
    for (int r = 0; r < 4; ++r) {
        int gr = bm + ty * 4 + r;
        if (gr < M) {
            unsigned* rowp = hevu + (size_t)gr * 128;
#pragma unroll
            for (int p = 0; p < 4; ++p) {
                rowp[((tx * 4 + p) << 1) + OFFH] = bf16pair(acc[r][2 * p], acc[r][2 * p + 1]);
            }
        }
    }
}

// ---------------- per-node scalars s1,s2,t1 (wave per row, K=256) ----------------
__global__ void node_scalars(const float* __restrict__ NF, const float* __restrict__ w1,
                             const float* __restrict__ w2, const float* __restrict__ w3,
                             float* __restrict__ s1, float* __restrict__ s2, float* __restrict__ t1) {
    int wave = (int)((blockIdx.x * (size_t)blockDim.x + threadIdx.x) >> 6);
    int lane = threadIdx.x & 63;
    if (wave >= NN) return;
    const float* row = NF + (size_t)wave * 256;
    float4 v = *reinterpret_cast<const float4*>(row + lane * 4);
    float a = 0.f, b = 0.f, c = 0.f;
    const float* x = reinterpret_cast<const float*>(&v);
#pragma unroll
    for (int j = 0; j < 4; ++j) {
        a += x[j] * w1[lane * 4 + j];
        b += x[j] * w2[lane * 4 + j];
        c += x[j] * w3[lane * 4 + j];
    }
    for (int off = 32; off; off >>= 1) {
        a += __shfl_down(a, off);
        b += __shfl_down(b, off);
        c += __shfl_down(c, off);
    }
    if (lane == 0) { s1[wave] = a; s2[wave] = b; t1[wave] = c; }
}

// ---------------- per-edge scalar t2e (wave per row, K=128) ----------------
__global__ void edge_scalar(const float* __restrict__ EF, const float* __restrict__ w,
                            float* __restrict__ t2e) {
    int wave = (int)((blockIdx.x * (size_t)blockDim.x + threadIdx.x) >> 6);
    int lane = threadIdx.x & 63;
    if (wave >= EE) return;
    float2 v = *reinterpret_cast<const float2*>(EF + (size_t)wave * 128 + lane * 2);
    float a = v.x * w[lane * 2] + v.y * w[lane * 2 + 1];
    for (int off = 32; off; off >>= 1) a += __shfl_down(a, off);
    if (lane == 0) t2e[wave] = a;
}

// ---------------- per-edge attention + segment sums + counts ----------------
__global__ void attention(const int* __restrict__ edges, const float* __restrict__ s1,
                          const float* __restrict__ s2, const float* __restrict__ t1,
                          const float* __restrict__ t2e, float* __restrict__ natt,
                          float* __restrict__ eatt, float* __restrict__ nsum,
                          float* __restrict__ esum, int* __restrict__ counts) {
    int i = blockIdx.x * blockDim.x + threadIdx.x;
    if (i >= 2 * EE) return;
    int s, d, j;
    if (i < EE) { j = i; int2 p = *reinterpret_cast<const int2*>(edges + 2 * j); s = p.x; d = p.y; }
    else        { j = i - EE; int2 p = *reinterpret_cast<const int2*>(edges + 2 * j); s = p.y; d = p.x; }
    float xn = s1[s] + s2[d];
    xn = xn >= 0.f ? xn : 0.2f * xn;
    xn = fminf(fmaxf(xn, -2.f), 2.f);
    float na = expf(xn);
    float xe = t1[s] + t2e[j];
    xe = xe >= 0.f ? xe : 0.2f * xe;
    xe = fminf(fmaxf(xe, -2.f), 2.f);
    float ea = expf(xe);
    natt[i] = na; eatt[i] = ea;
    atomicAdd(&nsum[s], na);
    atomicAdd(&esum[s], ea);
    atomicAdd(&counts[s], 1);
}

// ---------------- scan: counts -> offsets (exclusive), cursor copy ----------------
#define SCAN_CHUNK 2048
__global__ void scan_block_sums(const int* __restrict__ counts, int* __restrict__ bsums) {
    __shared__ int sdata[256];
    int b = blockIdx.x, t = threadIdx.x;
    int base = b * SCAN_CHUNK + t * 8;
    int s = 0;
    for (int j = 0; j < 8; ++j) { int idx = base + j; if (idx < NN) s += counts[idx]; }
    sdata[t] = s; __syncthreads();
    for (int off = 128; off; off >>= 1) { if (t < off) sdata[t] += sdata[t + off]; __syncthreads(); }
    if (t == 0) bsums[b] = sdata[0];
}
__global__ void scan_bsums(int* __restrict__ bsums, int nb) {
    if (threadIdx.x == 0 && blockIdx.x == 0) {
        int run = 0;
        for (int i = 0; i < nb; ++i) { int v = bsums[i]; bsums[i] = run; run += v; }
    }
}
__global__ void scan_final(const int* __restrict__ counts, const int* __restrict__ bsums,
                           int* __restrict__ offsets, int* __restrict__ cursor) {
    __shared__ int sdata[256];
    int b = blockIdx.x, t = threadIdx.x;
    int base = b * SCAN_CHUNK + t * 8;
    int loc[8]; int s = 0;
    for (int j = 0; j < 8; ++j) { int idx = base + j; int v = (idx < NN) ? counts[idx] : 0; loc[j] = v; s += v; }
    sdata[t] = s; __syncthreads();
    for (int off = 1; off < 256; off <<= 1) {
        int v = (t >= off) ? sdata[t - off] : 0;
        __syncthreads();
        sdata[t] += v;
        __syncthreads();
    }
    int run = sdata[t] - s + bsums[b];
    for (int j = 0; j < 8; ++j) {
        int idx = base + j;
        if (idx < NN) { offsets[idx] = run; cursor[idx] = run; run += loc[j]; }
    }
}

// ---------------- fill position->node map g ----------------
__global__ void fill_g(const int* __restrict__ offsets, const int* __restrict__ counts,
                       int* __restrict__ g) {
    int n = blockIdx.x * blockDim.x + threadIdx.x;
    if (n >= NN) return;
    int o = offsets[n], c = counts[n];
    for (int k = 0; k < c; ++k) g[o + k] = n;
}

// ---------------- normalize + CSR meta scatter + variance partials ----------------
__global__ void normalize_var(const float* __restrict__ natt, const float* __restrict__ eatt,
                              const float* __restrict__ nsum, const float* __restrict__ esum,
                              const int* __restrict__ g, const int* __restrict__ edges,
                              int* __restrict__ cursor, float4* __restrict__ meta,
                              double* __restrict__ acc) {
    int i = blockIdx.x * blockDim.x + threadIdx.x;
    float nn = 0.f, en = 0.f;
    if (i < 2 * EE) {
        int gi = g[i];
        nn = natt[i] / nsum[gi];
        en = eatt[i] / esum[gi];
        int s, d;
        if (i < EE) { int2 p = *reinterpret_cast<const int2*>(edges + 2 * i); s = p.x; d = p.y; }
        else        { int2 p = *reinterpret_cast<const int2*>(edges + 2 * (i - EE)); s = p.y; d = p.x; }
        int p = atomicAdd(&cursor[s], 1);
        meta[p] = make_float4(__int_as_float(d), nn, en, 0.f);
    }
    double v[4] = { (double)nn, (double)nn * nn, (double)en, (double)en * en };
    __shared__ double sd[4][4];
    int lane = threadIdx.x & 63, wv = threadIdx.x >> 6;
#pragma unroll
    for (int q = 0; q < 4; ++q) {
        double x = v[q];
        for (int off = 32; off; off >>= 1) x += __shfl_down(x, off);
        if (lane == 0) sd[q][wv] = x;
    }
    __syncthreads();
    if (threadIdx.x < 4) {
        double x = sd[threadIdx.x][0] + sd[threadIdx.x][1] + sd[threadIdx.x][2] + sd[threadIdx.x][3];
        atomicAdd(&acc[threadIdx.x], x);
    }
}

// ---------------- CSR accumulate: wave per node, bf16 hev gathers ----------------
__global__ void accumulate(const float4* __restrict__ meta, const int* __restrict__ offsets,
                           const int* __restrict__ counts, const uint2* __restrict__ hev,
                           float* __restrict__ node_out, float* __restrict__ edge_out) {
    int wave = (int)((blockIdx.x * (size_t)blockDim.x + threadIdx.x) >> 6);
    int lane = threadIdx.x & 63;
    if (wave >= NN) return;
    int o = offsets[wave], c = counts[wave];
    float aH0 = 0.f, aH1 = 0.f, aE0 = 0.f, aE1 = 0.f;
    float4 m0 = make_float4(0.f, 0.f, 0.f, 0.f), m1 = m0;
    if (c > 0) m0 = meta[o];
    if (c > 1) m1 = meta[o + 1];
    for (int k = 0; k < c; ++k) {
        float4 mnext = (k + 2 < c) ? meta[o + k + 2] : m1;
        int d = __float_as_int(m0.x);
        uint2 v = hev[(size_t)d * 64 + lane];
        float h0 = __uint_as_float(v.x << 16);
        float h1 = __uint_as_float(v.x & 0xFFFF0000u);
        float e0 = __uint_as_float(v.y << 16);
        float e1 = __uint_as_float(v.y & 0xFFFF0000u);
        aH0 += h0 * m0.y; aH1 += h1 * m0.y;
        aE0 += e0 * m0.z; aE1 += e1 * m0.z;
        m0 = m1; m1 = mnext;
    }
    float2 rn = { aH0, aH1 }, re = { aE0, aE1 };
    *reinterpret_cast<float2*>(node_out + (size_t)wave * 128 + lane * 2) = rn;
    *reinterpret_cast<float2*>(edge_out + (size_t)wave * 128 + lane * 2) = re;
}

// ---------------- finalize variance ----------------
__global__ void finalize_var(const double* __restrict__ acc, float* __restrict__ out_var) {
    if (threadIdx.x == 0 && blockIdx.x == 0) {
        double M = 2.0 * EE;
        double nv = (acc[1] - acc[0] * acc[0] / M) / (M - 1.0);
        double ev = (acc[3] - acc[2] * acc[2] / M) / (M - 1.0);
        out_var[0] = (float)nv;
        out_var[1] = (float)ev;
    }
}

extern "C" void kernel_launch(void* const* d_in, const int* in_sizes, int n_in,
                              void* d_out, int out_size, void* d_ws, size_t ws_size,
                              hipStream_t stream) {
    const float* node_fts = (const float*)d_in[0];
    const float* edge_fts = (const float*)d_in[1];
    const int*   edges    = (const int*)d_in[2];
    const float* W_node   = (const float*)d_in[3];
    const float* W_edge   = (const float*)d_in[4];
    const float* a_node   = (const float*)d_in[5];
    const float* a_edge   = (const float*)d_in[6];
    float* out = (float*)d_out;

    char* w = (char*)d_ws;
    auto alloc = [&](size_t bytes) -> void* {
        void* p = (void*)w;
        w += (bytes + 255) & ~(size_t)255;
        return p;
    };
    unsigned* hevu = (unsigned*)alloc((size_t)NN * 512);        // bf16 interleaved h/e rows
    float* s1    = (float*)alloc(NN * 4);
    float* s2    = (float*)alloc(NN * 4);
    float* t1    = (float*)alloc(NN * 4);
    float* t2e   = (float*)alloc(EE * 4);
    float* natt  = (float*)alloc(2 * EE * 4);
    float* eatt  = (float*)alloc(2 * EE * 4);
    float4* meta = (float4*)alloc((size_t)2 * EE * 16);
    int*   offsets = (int*)alloc((NN + 1) * 4);
    int*   cursor  = (int*)alloc(NN * 4);
    int*   g       = (int*)alloc(2 * EE * 4);
    int*   bsums   = (int*)alloc(64 * 4);
    float* wn_a1 = (float*)alloc(256 * 4);
    float* wn_a2 = (float*)alloc(256 * 4);
    float* wn_e1 = (float*)alloc(256 * 4);
    float* we_a2 = (float*)alloc(128 * 4);
    // contiguous zero block: nsum, esum (floats), counts (ints), acc (4 doubles)
    char* zb = (char*)alloc((size_t)NN * 12 + 64);
    float* nsum = (float*)zb;
    float* esum = (float*)(zb + (size_t)NN * 4);
    int*   counts = (int*)(zb + (size_t)NN * 8);
    double* acc = (double*)(zb + (size_t)NN * 12);

    hipMemsetAsync(zb, 0, (size_t)NN * 12 + 64, stream);

    prep_vectors<<<1, 256, 0, stream>>>(W_node, W_edge, a_node, a_edge, wn_a1, wn_a2, wn_e1, we_a2);

    const int gemm_grid = (NN + 63) / 64;  // 782
    gemm_f32<256, 0><<<gemm_grid, 256, 0, stream>>>(node_fts, W_node, hevu, NN);
    gemm_f32<128, 1><<<gemm_grid, 256, 0, stream>>>(edge_fts, W_edge, hevu, NN);

    node_scalars<<<(NN + 3) / 4, 256, 0, stream>>>(node_fts, wn_a1, wn_a2, wn_e1, s1, s2, t1);
    edge_scalar<<<(EE + 3) / 4, 256, 0, stream>>>(edge_fts, we_a2, t2e);

    attention<<<(2 * EE + 255) / 256, 256, 0, stream>>>(edges, s1, s2, t1, t2e, natt, eatt, nsum, esum, counts);

    const int nscan = (NN + SCAN_CHUNK - 1) / SCAN_CHUNK;  // 25
    scan_block_sums<<<nscan, 256, 0, stream>>>(counts, bsums);
    scan_bsums<<<1, 64, 0, stream>>>(bsums, nscan);
    scan_final<<<nscan, 256, 0, stream>>>(counts, bsums, offsets, cursor);

    fill_g<<<(NN + 255) / 256, 256, 0, stream>>>(offsets, counts, g);

    normalize_var<<<(2 * EE + 255) / 256, 256, 0, stream>>>(natt, eatt, nsum, esum, g, edges,
                                                            cursor, meta, acc);

    accumulate<<<(NN + 3) / 4, 256, 0, stream>>>(meta, offsets, counts, hevu ? (const uint2*)hevu : nullptr,
                                                 out, out + (size_t)NN * 128);

    finalize_var<<<1, 64, 0, stream>>>(acc, out + (size_t)2 * NN * 128);
}